// Round 8
// baseline (269.924 us; speedup 1.0000x reference)
//
#include <hip/hip_runtime.h>

#define DEV __device__ __forceinline__
#define KSIG (-1.442695041f)
#define KTANH (-2.885390082f)

typedef float f2 __attribute__((ext_vector_type(2)));

DEV float fexp2(float x) { return __builtin_amdgcn_exp2f(x); }
DEV float frcp(float x) { return __builtin_amdgcn_rcpf(x); }
DEV float bperm(int a, float x) {
  return __int_as_float(__builtin_amdgcn_ds_bpermute(a, __float_as_int(x)));
}
DEV f2 pkfma(f2 a, f2 b, f2 c) { return __builtin_elementwise_fma(a, b, c); }

// Anti-rematerialization pins: asm-defined values can't be re-derived from
// memory, so with a live-set that FITS the VGPR cap the allocator keeps them
// resident instead of re-loading weights inside the 128-step loop.
// (r4 evidence: wave0's pinned 48-float set fit at VGPR=76; every config
// whose live set exceeded the cap thrashed and stayed at ~115-145us.)
DEV void pinf(float& x) { asm volatile("" : "+v"(x)); }
DEV void pin2(f2& v) {
  float a = v.x, b = v.y;
  asm volatile("" : "+v"(a), "+v"(b));
  v = (f2){a, b};
}

// Lane u of a 5-lane group owns state index j=u and gate rows
// {u,5+u,10+u,15+u} (i,f,g,o). kexp folded into weights/bias: sigmoid rows
// scaled by KSIG, g-row by KTANH; act = rcp(1+exp2(acc)), tanh = 2*act-1.
// 48 floats/lane.
struct CellP {
  f2 wx[4][2];
  f2 wh[4][2];
  float wx4[4], wh4[4];
  f2 b2[4];  // {bias, 0}
};

DEV void load_cellP(CellP& W, int u, const float* __restrict__ Wih,
                    const float* __restrict__ Whh,
                    const float* __restrict__ bih,
                    const float* __restrict__ bhh) {
#pragma unroll
  for (int rt = 0; rt < 4; ++rt) {  // 0=i 1=f 2=g 3=o
    int row = 5 * rt + u;
    float kx = (rt == 2) ? KTANH : KSIG;
    W.wx[rt][0] = (f2){kx * Wih[row * 5 + 0], kx * Wih[row * 5 + 1]};
    W.wx[rt][1] = (f2){kx * Wih[row * 5 + 2], kx * Wih[row * 5 + 3]};
    W.wx4[rt] = kx * Wih[row * 5 + 4];
    W.wh[rt][0] = (f2){kx * Whh[row * 5 + 0], kx * Whh[row * 5 + 1]};
    W.wh[rt][1] = (f2){kx * Whh[row * 5 + 2], kx * Whh[row * 5 + 3]};
    W.wh4[rt] = kx * Whh[row * 5 + 4];
    W.b2[rt] = (f2){kx * (bih[row] + bhh[row]), 0.f};
  }
#pragma unroll
  for (int rt = 0; rt < 4; ++rt) {  // pin resident
    pin2(W.wx[rt][0]);
    pin2(W.wx[rt][1]);
    pin2(W.wh[rt][0]);
    pin2(W.wh[rt][1]);
    pin2(W.b2[rt]);
    pinf(W.wx4[rt]);
    pinf(W.wh4[rt]);
  }
}

// One cell timestep. Accumulation order: x-part FIRST (independent of the
// h(t-1) bperm results), h-part LAST — so the ~120cy bperm latency from the
// previous step hides under the x FMAs.
DEV float stepP(const CellP& W, const f2 xp[2], float x4, float hAll[5],
                float& c, const int bp[5]) {
  f2 hp0 = (f2){hAll[0], hAll[1]};
  f2 hp1 = (f2){hAll[2], hAll[3]};
  float acc[4];
#pragma unroll
  for (int rt = 0; rt < 4; ++rt) {
    f2 a2 = pkfma(W.wx[rt][0], xp[0], W.b2[rt]);
    a2 = pkfma(W.wx[rt][1], xp[1], a2);
    float s = W.wx4[rt] * x4;
    a2 = pkfma(W.wh[rt][0], hp0, a2);  // waits on bperm of h(t-1)
    a2 = pkfma(W.wh[rt][1], hp1, a2);
    s = fmaf(W.wh4[rt], hAll[4], s);
    acc[rt] = a2.x + a2.y + s;
  }
  float gi = frcp(1.f + fexp2(acc[0]));
  float gf = frcp(1.f + fexp2(acc[1]));
  float gg = fmaf(2.f, frcp(1.f + fexp2(acc[2])), -1.f);
  float go = frcp(1.f + fexp2(acc[3]));
  c = fmaf(gf, c, gi * gg);
  float th = fmaf(2.f, frcp(1.f + fexp2(KTANH * c)), -1.f);
  float h = go * th;
#pragma unroll
  for (int u2 = 0; u2 < 5; ++u2) hAll[u2] = bperm(bp[u2], h);
  return h;
}

// ---------------------------------------------------------------------------
// Kernel A: ONE wave per block (64 threads), ONE cell per wave, 12 elements.
// blockIdx < N1 -> lstm1 (writes h1l[B][5]); else lstm2a (streams h2a[e][t][5]).
// No LDS, no barriers, no XBuf: live set = 48 pinned weights + ~35 state/addr
// fits the 128-VGPR cap of __launch_bounds__(64,4) -> nothing to remat.
// 2731 one-wave blocks pack densely across 1024 SIMDs.
// ---------------------------------------------------------------------------
__global__ __launch_bounds__(64, 4) void rnn_a_kernel(
    const float* __restrict__ x1, const float* __restrict__ x2,
    const float* __restrict__ Wih1, const float* __restrict__ Whh1,
    const float* __restrict__ bih1, const float* __restrict__ bhh1,
    const float* __restrict__ Wih2a, const float* __restrict__ Whh2a,
    const float* __restrict__ bih2a, const float* __restrict__ bhh2a,
    float* __restrict__ h2a, float* __restrict__ h1l, int B, int N1) {
  const int l = threadIdx.x;
  int g = l / 5;
  const int u = l - 5 * g;
  const bool act = (g < 12);
  if (!act) g = 11;
  const bool r2 = (blockIdx.x >= N1);
  const int e = (r2 ? blockIdx.x - N1 : blockIdx.x) * 12 + g;
  const int ec = (e < B) ? e : B - 1;

  CellP W;
  if (r2)
    load_cellP(W, u, Wih2a, Whh2a, bih2a, bhh2a);
  else
    load_cellP(W, u, Wih1, Whh1, bih1, bhh1);

  int bp[5];
#pragma unroll
  for (int k = 0; k < 5; ++k) bp[k] = (5 * g + k) * 4;

  const float* px = (r2 ? x2 : x1) + (size_t)ec * 640;
  const bool wr = r2 && act && (e < B);
  float* ps = h2a + (size_t)ec * 640 + u;  // [e][t][5], this lane's j=u

  float hAll[5];
  float c = 0.f, hOwn = 0.f;
#pragma unroll
  for (int k = 0; k < 5; ++k) hAll[k] = 0.f;

  f2 xp[2] = {(f2){px[0], px[1]}, (f2){px[2], px[3]}};
  float x4 = px[4];
  for (int t = 0; t < 128; ++t) {
    f2 xi[2] = {xp[0], xp[1]};
    float xi4 = x4;
    const int tn = (t < 127) ? t + 1 : 127;  // prefetch x(t+1)
    xp[0] = (f2){px[tn * 5 + 0], px[tn * 5 + 1]};
    xp[1] = (f2){px[tn * 5 + 2], px[tn * 5 + 3]};
    x4 = px[tn * 5 + 4];
    hOwn = stepP(W, xi, xi4, hAll, c, bp);
    if (wr) ps[t * 5] = hOwn;
  }

  if (!r2 && act && e < B) h1l[(size_t)e * 5 + u] = hOwn;  // h1(127)
}

// ---------------------------------------------------------------------------
// Kernel B: ONE wave per block, lstm2b over the h2a stream + fused FC stack.
// ---------------------------------------------------------------------------
__global__ __launch_bounds__(64, 4) void rnn_b_kernel(
    const float* __restrict__ x1, const float* __restrict__ x2,
    const float* __restrict__ Wih2b, const float* __restrict__ Whh2b,
    const float* __restrict__ bih2b, const float* __restrict__ bhh2b,
    const float* __restrict__ W1, const float* __restrict__ b1,
    const float* __restrict__ W2, const float* __restrict__ b2,
    const float* __restrict__ W3, const float* __restrict__ b3,
    const float* __restrict__ W4, const float* __restrict__ b4,
    const float* __restrict__ W5, const float* __restrict__ b5,
    const float* __restrict__ h2a, const float* __restrict__ h1l,
    float* __restrict__ out, int B) {
  __shared__ float sIn[12][20];
  __shared__ float sA[12][32];
  __shared__ float sB[12][32];

  const int l = threadIdx.x;
  int g = l / 5;
  const int u = l - 5 * g;
  const bool act = (g < 12);
  if (!act) g = 11;
  const int e = blockIdx.x * 12 + g;
  const int ec = (e < B) ? e : B - 1;

  CellP W;
  load_cellP(W, u, Wih2b, Whh2b, bih2b, bhh2b);

  int bp[5];
#pragma unroll
  for (int k = 0; k < 5; ++k) bp[k] = (5 * g + k) * 4;

  const float* ph = h2a + (size_t)ec * 640;  // this element's h2a(t) stream

  float hAll[5];
  float c = 0.f, hOwn = 0.f;
#pragma unroll
  for (int k = 0; k < 5; ++k) hAll[k] = 0.f;

  f2 xp[2] = {(f2){ph[0], ph[1]}, (f2){ph[2], ph[3]}};
  float x4 = ph[4];
  for (int t = 0; t < 128; ++t) {
    f2 xi[2] = {xp[0], xp[1]};
    float xi4 = x4;
    const int tn = (t < 127) ? t + 1 : 127;  // prefetch h2a(t+1)
    xp[0] = (f2){ph[tn * 5 + 0], ph[tn * 5 + 1]};
    xp[1] = (f2){ph[tn * 5 + 2], ph[tn * 5 + 3]};
    x4 = ph[tn * 5 + 4];
    hOwn = stepP(W, xi, xi4, hAll, c, bp);
  }

  // Stage FC inputs [x1_last, x2_last, h1, h2b] for the block's 12 elements.
  if (act) {
    sIn[g][u] = x1[(size_t)ec * 640 + 635 + u];
    sIn[g][5 + u] = x2[(size_t)ec * 640 + 635 + u];
    sIn[g][10 + u] = h1l[(size_t)ec * 5 + u];
    sIn[g][15 + u] = hOwn;  // h2b(127)
  }
  __syncthreads();

  // FC stack: task-split over 64 lanes; weights from global (L1-cached).
  for (int task = l; task < 12 * 32; task += 64) {
    int e2 = task >> 5, n = task & 31;
    float acc = b1[n];
#pragma unroll
    for (int k = 0; k < 20; ++k) acc = fmaf(W1[n * 20 + k], sIn[e2][k], acc);
    sA[e2][n] = fmaxf(acc, 0.f);
  }
  __syncthreads();
  for (int task = l; task < 12 * 32; task += 64) {
    int e2 = task >> 5, n = task & 31;
    float acc = b2[n];
#pragma unroll
    for (int k = 0; k < 32; ++k) acc = fmaf(W2[n * 32 + k], sA[e2][k], acc);
    sB[e2][n] = fmaxf(acc, 0.f);
  }
  __syncthreads();
  for (int task = l; task < 12 * 16; task += 64) {
    int e2 = task >> 4, n = task & 15;
    float acc = b3[n];
#pragma unroll
    for (int k = 0; k < 32; ++k) acc = fmaf(W3[n * 32 + k], sB[e2][k], acc);
    sA[e2][n] = fmaxf(acc, 0.f);  // reuse sA cols 0..15
  }
  __syncthreads();
  for (int task = l; task < 12 * 16; task += 64) {
    int e2 = task >> 4, n = task & 15;
    float acc = b4[n];
#pragma unroll
    for (int k = 0; k < 16; ++k) acc = fmaf(W4[n * 16 + k], sA[e2][k], acc);
    sB[e2][n] = fmaxf(acc, 0.f);
  }
  __syncthreads();
  if (l < 60) {  // 12 elems x 5 outputs
    int e2 = l / 5, n = l - 5 * (l / 5);
    float acc = b5[n];
#pragma unroll
    for (int k = 0; k < 16; ++k) acc = fmaf(W5[n * 16 + k], sB[e2][k], acc);
    int ego = blockIdx.x * 12 + e2;
    if (ego < B) out[(size_t)ego * 5 + n] = acc;
  }
}

// ---------------------------------------------------------------------------
// Fallback (round-3 monolith, measured 119.5us) if workspace is too small.
// ---------------------------------------------------------------------------
__global__ __launch_bounds__(192, 2) void rnn_stag_kernel(
    const float* __restrict__ x1, const float* __restrict__ x2,
    const float* __restrict__ Wih1, const float* __restrict__ Whh1,
    const float* __restrict__ bih1, const float* __restrict__ bhh1,
    const float* __restrict__ Wih2a, const float* __restrict__ Whh2a,
    const float* __restrict__ bih2a, const float* __restrict__ bhh2a,
    const float* __restrict__ Wih2b, const float* __restrict__ Whh2b,
    const float* __restrict__ bih2b, const float* __restrict__ bhh2b,
    const float* __restrict__ W1, const float* __restrict__ b1,
    const float* __restrict__ W2, const float* __restrict__ b2,
    const float* __restrict__ W3, const float* __restrict__ b3,
    const float* __restrict__ W4, const float* __restrict__ b4,
    const float* __restrict__ W5, const float* __restrict__ b5,
    float* __restrict__ out, int B) {
  __shared__ float sIn[24][20];
  __shared__ float sA[24][32];
  __shared__ float sB[24][32];

  const int tid = threadIdx.x;
  const int w = tid >> 6;
  const int l = tid & 63;
  int g = l / 5;
  const int u = l - 5 * g;
  const bool act = (g < 12);
  if (!act) g = 11;
  const int base = blockIdx.x * 24;

  int bp[5];
#pragma unroll
  for (int k = 0; k < 5; ++k) bp[k] = (5 * g + k) * 4;

  if (w == 0) {
    CellP W;
    load_cellP(W, u, Wih1, Whh1, bih1, bhh1);
    const int e0 = base + 2 * g, e1 = e0 + 1;
    const int e0c = (e0 < B) ? e0 : B - 1;
    const int e1c = (e1 < B) ? e1 : B - 1;
    const float* p0 = x1 + (size_t)e0c * 640;
    const float* p1 = x1 + (size_t)e1c * 640;
    float h0[5], h1[5];
    float c0 = 0.f, c1 = 0.f, ho0 = 0.f, ho1 = 0.f;
#pragma unroll
    for (int k = 0; k < 5; ++k) {
      h0[k] = 0.f;
      h1[k] = 0.f;
    }
    f2 xa[2] = {(f2){p0[0], p0[1]}, (f2){p0[2], p0[3]}};
    f2 xb[2] = {(f2){p1[0], p1[1]}, (f2){p1[2], p1[3]}};
    float xa4 = p0[4], xb4 = p1[4];
    for (int t = 0; t < 128; ++t) {
      f2 xia[2] = {xa[0], xa[1]}, xib[2] = {xb[0], xb[1]};
      float xia4 = xa4, xib4 = xb4;
      const int tn = (t < 127) ? t + 1 : 127;
      xa[0] = (f2){p0[tn * 5 + 0], p0[tn * 5 + 1]};
      xa[1] = (f2){p0[tn * 5 + 2], p0[tn * 5 + 3]};
      xa4 = p0[tn * 5 + 4];
      xb[0] = (f2){p1[tn * 5 + 0], p1[tn * 5 + 1]};
      xb[1] = (f2){p1[tn * 5 + 2], p1[tn * 5 + 3]};
      xb4 = p1[tn * 5 + 4];
      ho0 = stepP(W, xia, xia4, h0, c0, bp);
      ho1 = stepP(W, xib, xib4, h1, c1, bp);
    }
    if (act) {
      sIn[2 * g][u] = x1[(size_t)e0c * 640 + 635 + u];
      sIn[2 * g][10 + u] = ho0;
      sIn[2 * g + 1][u] = x1[(size_t)e1c * 640 + 635 + u];
      sIn[2 * g + 1][10 + u] = ho1;
    }
  } else {
    CellP Wa, Wb;
    load_cellP(Wa, u, Wih2a, Whh2a, bih2a, bhh2a);
    load_cellP(Wb, u, Wih2b, Whh2b, bih2b, bhh2b);
    const int el = ((w == 1) ? 0 : 12) + g;
    const int e = base + el;
    const int ec = (e < B) ? e : B - 1;
    const float* px = x2 + (size_t)ec * 640;
    float hA[5], hB[5];
    float cA = 0.f, cB = 0.f, hoB = 0.f;
#pragma unroll
    for (int k = 0; k < 5; ++k) {
      hA[k] = 0.f;
      hB[k] = 0.f;
    }
    f2 xc[2] = {(f2){px[0], px[1]}, (f2){px[2], px[3]}};
    float xc4 = px[4];
    (void)stepP(Wa, xc, xc4, hA, cA, bp);
    xc[0] = (f2){px[5], px[6]};
    xc[1] = (f2){px[7], px[8]};
    xc4 = px[9];
    for (int t = 1; t < 128; ++t) {
      f2 xin[2] = {xc[0], xc[1]};
      float xin4 = xc4;
      const int tn = (t < 127) ? t + 1 : 127;
      xc[0] = (f2){px[tn * 5 + 0], px[tn * 5 + 1]};
      xc[1] = (f2){px[tn * 5 + 2], px[tn * 5 + 3]};
      xc4 = px[tn * 5 + 4];
      f2 hin[2] = {(f2){hA[0], hA[1]}, (f2){hA[2], hA[3]}};
      float hin4 = hA[4];
      (void)stepP(Wa, xin, xin4, hA, cA, bp);
      hoB = stepP(Wb, hin, hin4, hB, cB, bp);
    }
    {
      f2 hin[2] = {(f2){hA[0], hA[1]}, (f2){hA[2], hA[3]}};
      hoB = stepP(Wb, hin, hA[4], hB, cB, bp);
    }
    if (act) {
      sIn[el][5 + u] = x2[(size_t)ec * 640 + 635 + u];
      sIn[el][15 + u] = hoB;
    }
  }
  __syncthreads();

  for (int task = tid; task < 24 * 32; task += 192) {
    int e = task >> 5, n = task & 31;
    float acc = b1[n];
#pragma unroll
    for (int k = 0; k < 20; ++k) acc = fmaf(W1[n * 20 + k], sIn[e][k], acc);
    sA[e][n] = fmaxf(acc, 0.f);
  }
  __syncthreads();
  for (int task = tid; task < 24 * 32; task += 192) {
    int e = task >> 5, n = task & 31;
    float acc = b2[n];
#pragma unroll
    for (int k = 0; k < 32; ++k) acc = fmaf(W2[n * 32 + k], sA[e][k], acc);
    sB[e][n] = fmaxf(acc, 0.f);
  }
  __syncthreads();
  for (int task = tid; task < 24 * 16; task += 192) {
    int e = task >> 4, n = task & 15;
    float acc = b3[n];
#pragma unroll
    for (int k = 0; k < 32; ++k) acc = fmaf(W3[n * 32 + k], sB[e][k], acc);
    sA[e][n] = fmaxf(acc, 0.f);
  }
  __syncthreads();
  for (int task = tid; task < 24 * 16; task += 192) {
    int e = task >> 4, n = task & 15;
    float acc = b4[n];
#pragma unroll
    for (int k = 0; k < 16; ++k) acc = fmaf(W4[n * 16 + k], sA[e][k], acc);
    sB[e][n] = fmaxf(acc, 0.f);
  }
  __syncthreads();
  if (tid < 120) {
    int e = tid / 5, n = tid - 5 * (tid / 5);
    float acc = b5[n];
#pragma unroll
    for (int k = 0; k < 16; ++k) acc = fmaf(W5[n * 16 + k], sB[e][k], acc);
    int ego = base + e;
    if (ego < B) out[(size_t)ego * 5 + n] = acc;
  }
}

extern "C" void kernel_launch(void* const* d_in, const int* in_sizes, int n_in,
                              void* d_out, int out_size, void* d_ws,
                              size_t ws_size, hipStream_t stream) {
  const float* x1 = (const float*)d_in[0];
  const float* x2 = (const float*)d_in[1];
  const float* Wih1 = (const float*)d_in[2];
  const float* Whh1 = (const float*)d_in[3];
  const float* bih1 = (const float*)d_in[4];
  const float* bhh1 = (const float*)d_in[5];
  const float* Wih2a = (const float*)d_in[6];
  const float* Whh2a = (const float*)d_in[7];
  const float* bih2a = (const float*)d_in[8];
  const float* bhh2a = (const float*)d_in[9];
  const float* Wih2b = (const float*)d_in[10];
  const float* Whh2b = (const float*)d_in[11];
  const float* bih2b = (const float*)d_in[12];
  const float* bhh2b = (const float*)d_in[13];
  const float* W1 = (const float*)d_in[14];
  const float* b1 = (const float*)d_in[15];
  const float* W2 = (const float*)d_in[16];
  const float* b2 = (const float*)d_in[17];
  const float* W3 = (const float*)d_in[18];
  const float* b3 = (const float*)d_in[19];
  const float* W4 = (const float*)d_in[20];
  const float* b4 = (const float*)d_in[21];
  const float* W5 = (const float*)d_in[22];
  const float* b5 = (const float*)d_in[23];

  int B = in_sizes[0] / 640;  // [B,128,5]
  size_t req = ((size_t)B * 640 + (size_t)B * 5) * sizeof(float);

  if (d_ws && ws_size >= req) {
    float* h2a = (float*)d_ws;           // [B][128][5]
    float* h1l = h2a + (size_t)B * 640;  // [B][5]
    int N1 = (B + 11) / 12;              // 12 elems per wave, 1 wave per block
    rnn_a_kernel<<<2 * N1, 64, 0, stream>>>(x1, x2, Wih1, Whh1, bih1, bhh1,
                                            Wih2a, Whh2a, bih2a, bhh2a, h2a,
                                            h1l, B, N1);
    rnn_b_kernel<<<N1, 64, 0, stream>>>(x1, x2, Wih2b, Whh2b, bih2b, bhh2b, W1,
                                        b1, W2, b2, W3, b3, W4, b4, W5, b5,
                                        h2a, h1l, (float*)d_out, B);
  } else {
    int nB = (B + 23) / 24;
    rnn_stag_kernel<<<nB, 192, 0, stream>>>(
        x1, x2, Wih1, Whh1, bih1, bhh1, Wih2a, Whh2a, bih2a, bhh2a, Wih2b,
        Whh2b, bih2b, bhh2b, W1, b1, W2, b2, W3, b3, W4, b4, W5, b5,
        (float*)d_out, B);
  }
}

// Round 9
// 239.643 us; speedup vs baseline: 1.1264x; 1.1264x over previous
//
#include <hip/hip_runtime.h>

#define DEV __device__ __forceinline__
#define KSIG (-1.442695041f)
#define KTANH (-2.885390082f)

typedef float f4 __attribute__((ext_vector_type(4)));

DEV float fexp2(float x) { return __builtin_amdgcn_exp2f(x); }
DEV float frcp(float x) { return __builtin_amdgcn_rcpf(x); }
DEV float bperm(int a, float x) {
  return __int_as_float(__builtin_amdgcn_ds_bpermute(a, __float_as_int(x)));
}

// lgkm-only barrier: orders LDS (sH ring + bperm) across waves WITHOUT
// draining vmcnt, so the chunked global x-prefetch stays in flight across the
// per-timestep sync. (__syncthreads emits s_waitcnt vmcnt(0) lgkmcnt(0).)
// Wave-uniform: executed exactly 128x by each of the 3 waves.
DEV void sync_lds() {
  asm volatile("s_waitcnt lgkmcnt(0)\ns_barrier" ::: "memory");
}

// Lane u of a 5-lane group owns state index j=u and gate rows
// {u,5+u,10+u,15+u} (i,f,g,o). kexp folded in: sigmoid rows scaled by KSIG,
// g-row by KTANH; act = rcp(1+exp2(acc)), tanh = 2*act-1.
// ALL-SCALAR weights (44 floats): no f2 packing anywhere in the recurrence —
// pkfma operand marshaling (v_mov pairs to build even-aligned operands,
// a2.x+a2.y extracts) is the prime suspect for the ~50 extra inst/step seen
// in every round 0-8 (all used f2).
struct CellS {
  float wx[4][5];
  float wh[4][5];
  float b[4];
};

DEV void load_cellS(CellS& W, int u, const float* __restrict__ Wih,
                    const float* __restrict__ Whh,
                    const float* __restrict__ bih,
                    const float* __restrict__ bhh) {
#pragma unroll
  for (int rt = 0; rt < 4; ++rt) {  // 0=i 1=f 2=g 3=o
    int row = 5 * rt + u;
    float kx = (rt == 2) ? KTANH : KSIG;
#pragma unroll
    for (int k = 0; k < 5; ++k) {
      W.wx[rt][k] = kx * Wih[row * 5 + k];
      W.wh[rt][k] = kx * Whh[row * 5 + k];
    }
    W.b[rt] = kx * (bih[row] + bhh[row]);
  }
}

// One cell timestep, pure scalar fmaf chains. x-part FIRST, h-part LAST so the
// bperm (lgkm) results of the previous step are consumed as late as possible.
DEV float stepS(const CellS& W, float x0, float x1, float x2, float x3,
                float x4, float hAll[5], float& c, const int bp[5]) {
  float acc[4];
#pragma unroll
  for (int rt = 0; rt < 4; ++rt) {
    float a = W.b[rt];
    a = fmaf(W.wx[rt][0], x0, a);
    a = fmaf(W.wx[rt][1], x1, a);
    a = fmaf(W.wx[rt][2], x2, a);
    a = fmaf(W.wx[rt][3], x3, a);
    a = fmaf(W.wx[rt][4], x4, a);
    a = fmaf(W.wh[rt][0], hAll[0], a);
    a = fmaf(W.wh[rt][1], hAll[1], a);
    a = fmaf(W.wh[rt][2], hAll[2], a);
    a = fmaf(W.wh[rt][3], hAll[3], a);
    acc[rt] = fmaf(W.wh[rt][4], hAll[4], a);
  }
  float gi = frcp(1.f + fexp2(acc[0]));
  float gf = frcp(1.f + fexp2(acc[1]));
  float gg = fmaf(2.f, frcp(1.f + fexp2(acc[2])), -1.f);
  float go = frcp(1.f + fexp2(acc[3]));
  c = fmaf(gf, c, gi * gg);
  float th = fmaf(2.f, frcp(1.f + fexp2(KTANH * c)), -1.f);
  float h = go * th;
#pragma unroll
  for (int u2 = 0; u2 < 5; ++u2) hAll[u2] = bperm(bp[u2], h);
  return h;
}

// 4-timestep x chunk: 20 floats = 5 aligned dwordx4 (element base is 2560B
// aligned). Double-buffered; with lgkm-only barriers these loads stay in
// flight across per-step syncs (r7-proven: chunked prefetch = 77.5 vs 102us).
struct XBuf {
  f4 a, b, c, d, e;
};
DEV void xload(XBuf& bf, const float* __restrict__ px, int ch) {
  const f4* q = (const f4*)px + ch * 5;
  bf.a = q[0];
  bf.b = q[1];
  bf.c = q[2];
  bf.d = q[3];
  bf.e = q[4];
}
// Step s of a chunk consumes floats [5s..5s+4]:
//  s=0: a.xyzw b.x  s=1: b.yzw c.xy  s=2: c.zw d.xyz  s=3: d.w e.xyzw

// One timestep of the r0 pipeline. Global t = 4*chunk + S, so t&1 == S&1 is
// compile-time. w2 consumes h2a(t-1) from sH[(S+1)&1]; w1 publishes h2a(t)
// to sH[S&1]. RST discards w2's junk step at t==0 (sH was zeroed).
#define STEP_S(S, RST, X0, X1, X2, X3, X4)                    \
  {                                                           \
    float xv0, xv1, xv2, xv3, xv4;                            \
    if (w == 2) {                                             \
      const float* s = &sH[((S) + 1) & 1][g * 5];             \
      xv0 = s[0];                                             \
      xv1 = s[1];                                             \
      xv2 = s[2];                                             \
      xv3 = s[3];                                             \
      xv4 = s[4];                                             \
    } else {                                                  \
      xv0 = X0;                                               \
      xv1 = X1;                                               \
      xv2 = X2;                                               \
      xv3 = X3;                                               \
      xv4 = X4;                                               \
    }                                                         \
    hOwn = stepS(W, xv0, xv1, xv2, xv3, xv4, hAll, c, bp);    \
    if (w == 1 && act) sH[(S) & 1][g * 5 + u] = hOwn;         \
    if ((RST) && w == 2) {                                    \
      hAll[0] = hAll[1] = hAll[2] = hAll[3] = hAll[4] = 0.f;  \
      c = 0.f;                                                \
      hOwn = 0.f;                                             \
    }                                                         \
    sync_lds();                                               \
  }

#define CHUNK(X, RST)                                 \
  STEP_S(0, RST, X.a.x, X.a.y, X.a.z, X.a.w, X.b.x)   \
  STEP_S(1, false, X.b.y, X.b.z, X.b.w, X.c.x, X.c.y) \
  STEP_S(2, false, X.c.z, X.c.w, X.d.x, X.d.y, X.d.z) \
  STEP_S(3, false, X.d.w, X.e.x, X.e.y, X.e.z, X.e.w)

// Block = 192 threads = 3 waves, 12 elements (5 lanes each; lanes 60..63
// shadow group 11). Round-0's graded-best skeleton:
//   wave0: lstm1. wave1: lstm2a -> sH ring. wave2: lstm2b, one step behind.
// Changes vs r0 (isolated): scalar stepS, lgkm-only barrier, XBuf prefetch.
__global__ __launch_bounds__(192, 2) void rnn_s_kernel(
    const float* __restrict__ x1, const float* __restrict__ x2,
    const float* __restrict__ Wih1, const float* __restrict__ Whh1,
    const float* __restrict__ bih1, const float* __restrict__ bhh1,
    const float* __restrict__ Wih2a, const float* __restrict__ Whh2a,
    const float* __restrict__ bih2a, const float* __restrict__ bhh2a,
    const float* __restrict__ Wih2b, const float* __restrict__ Whh2b,
    const float* __restrict__ bih2b, const float* __restrict__ bhh2b,
    const float* __restrict__ W1, const float* __restrict__ b1,
    const float* __restrict__ W2, const float* __restrict__ b2,
    const float* __restrict__ W3, const float* __restrict__ b3,
    const float* __restrict__ W4, const float* __restrict__ b4,
    const float* __restrict__ W5, const float* __restrict__ b5,
    float* __restrict__ out, int B) {
  __shared__ float sH[2][64];  // h2a handoff ring: [buf][g*5+u]
  __shared__ float sIn[12][20];
  __shared__ float sA[12][32];
  __shared__ float sB[12][32];

  const int tid = threadIdx.x;
  const int w = tid >> 6;  // wave role: 0=lstm1 1=lstm2a 2=lstm2b
  const int l = tid & 63;
  int g = l / 5;
  const int u = l - 5 * g;
  const bool act = (g < 12);
  if (!act) g = 11;  // idle lanes shadow group 11 (results discarded)
  const int eg = blockIdx.x * 12 + g;
  const int egc = (eg < B) ? eg : (B - 1);

  CellS W;
  if (w == 0)
    load_cellS(W, u, Wih1, Whh1, bih1, bhh1);
  else if (w == 1)
    load_cellS(W, u, Wih2a, Whh2a, bih2a, bhh2a);
  else
    load_cellS(W, u, Wih2b, Whh2b, bih2b, bhh2b);

  int bp[5];
#pragma unroll
  for (int k = 0; k < 5; ++k) bp[k] = (5 * g + k) * 4;

  const float* px = ((w == 0) ? x1 : x2) + (size_t)egc * 640;

  if (tid < 128) sH[tid >> 6][tid & 63] = 0.f;

  float hAll[5];
  float c = 0.f, hOwn = 0.f;
#pragma unroll
  for (int k = 0; k < 5; ++k) hAll[k] = 0.f;

  XBuf cur{}, nxt{};
  if (w < 2) xload(cur, px, 0);
  __syncthreads();  // sH zeroed before wave2's first (junk) read

  for (int ch = 0; ch < 32; ch += 2) {
    if (w < 2) xload(nxt, px, (ch + 1 < 32) ? ch + 1 : 31);
    const bool rst = (ch == 0);
    CHUNK(cur, rst);
    if (w < 2) xload(cur, px, (ch + 2 < 32) ? ch + 2 : 31);
    CHUNK(nxt, false);
  }

  // wave2 trails by one: consume h2a(127) from sH[127&1]=sH[1]
  if (w == 2) {
    const float* s = &sH[1][g * 5];
    hOwn = stepS(W, s[0], s[1], s[2], s[3], s[4], hAll, c, bp);
  }

  // Stage FC inputs: [x1_last, x2_last, h1, h2b]
  if (act) {
    if (w == 0) {
      sIn[g][u] = x1[(size_t)egc * 640 + 635 + u];
      sIn[g][10 + u] = hOwn;  // h1(127), own j=u
    } else if (w == 1) {
      sIn[g][5 + u] = x2[(size_t)egc * 640 + 635 + u];
    } else {
      sIn[g][15 + u] = hOwn;  // h2b(127)
    }
  }
  __syncthreads();

  // FC stack: task-split over 192 lanes; weights from global (L1-cached).
  for (int task = tid; task < 12 * 32; task += 192) {
    int e = task >> 5, n = task & 31;
    float acc = b1[n];
#pragma unroll
    for (int k = 0; k < 20; ++k) acc = fmaf(W1[n * 20 + k], sIn[e][k], acc);
    sA[e][n] = fmaxf(acc, 0.f);
  }
  __syncthreads();
  for (int task = tid; task < 12 * 32; task += 192) {
    int e = task >> 5, n = task & 31;
    float acc = b2[n];
#pragma unroll
    for (int k = 0; k < 32; ++k) acc = fmaf(W2[n * 32 + k], sA[e][k], acc);
    sB[e][n] = fmaxf(acc, 0.f);
  }
  __syncthreads();
  {  // 12*16 = 192 tasks, exactly one per lane
    int e = tid >> 4, n = tid & 15;
    float acc = b3[n];
#pragma unroll
    for (int k = 0; k < 32; ++k) acc = fmaf(W3[n * 32 + k], sB[e][k], acc);
    sA[e][n] = fmaxf(acc, 0.f);  // reuse sA cols 0..15
  }
  __syncthreads();
  {
    int e = tid >> 4, n = tid & 15;
    float acc = b4[n];
#pragma unroll
    for (int k = 0; k < 16; ++k) acc = fmaf(W4[n * 16 + k], sA[e][k], acc);
    sB[e][n] = fmaxf(acc, 0.f);
  }
  __syncthreads();
  if (tid < 60) {  // 12 elems x 5 outputs
    int e = tid / 5, n = tid - 5 * (tid / 5);
    float acc = b5[n];
#pragma unroll
    for (int k = 0; k < 16; ++k) acc = fmaf(W5[n * 16 + k], sB[e][k], acc);
    int ego = blockIdx.x * 12 + e;
    if (ego < B) out[(size_t)ego * 5 + n] = acc;
  }
}

extern "C" void kernel_launch(void* const* d_in, const int* in_sizes, int n_in,
                              void* d_out, int out_size, void* d_ws,
                              size_t ws_size, hipStream_t stream) {
  const float* x1 = (const float*)d_in[0];
  const float* x2 = (const float*)d_in[1];
  const float* Wih1 = (const float*)d_in[2];
  const float* Whh1 = (const float*)d_in[3];
  const float* bih1 = (const float*)d_in[4];
  const float* bhh1 = (const float*)d_in[5];
  const float* Wih2a = (const float*)d_in[6];
  const float* Whh2a = (const float*)d_in[7];
  const float* bih2a = (const float*)d_in[8];
  const float* bhh2a = (const float*)d_in[9];
  const float* Wih2b = (const float*)d_in[10];
  const float* Whh2b = (const float*)d_in[11];
  const float* bih2b = (const float*)d_in[12];
  const float* bhh2b = (const float*)d_in[13];
  const float* W1 = (const float*)d_in[14];
  const float* b1 = (const float*)d_in[15];
  const float* W2 = (const float*)d_in[16];
  const float* b2 = (const float*)d_in[17];
  const float* W3 = (const float*)d_in[18];
  const float* b3 = (const float*)d_in[19];
  const float* W4 = (const float*)d_in[20];
  const float* b4 = (const float*)d_in[21];
  const float* W5 = (const float*)d_in[22];
  const float* b5 = (const float*)d_in[23];

  int B = in_sizes[0] / 640;  // [B,128,5]
  int nB = (B + 11) / 12;     // 12 elements per block

  rnn_s_kernel<<<nB, 192, 0, stream>>>(
      x1, x2, Wih1, Whh1, bih1, bhh1, Wih2a, Whh2a, bih2a, bhh2a, Wih2b, Whh2b,
      bih2b, bhh2b, W1, b1, W2, b2, W3, b3, W4, b4, W5, b5, (float*)d_out, B);
}